// Round 1
// baseline (775.660 us; speedup 1.0000x reference)
//
#include <hip/hip_runtime.h>
#include <stdint.h>

// ---------------------------------------------------------------------------
// TreeLayer: h = x @ M + x_init, M = tw^2*blockdiag + bbw*strict_block_upper
// (block-upper-triangular incl. diagonal), then per-column ActNorm + sigmoid.
// bf16 MFMA GEMM (threshold 1.99e-2 licenses bf16 compute).
// ---------------------------------------------------------------------------

#define BATCH 8192
#define DIM   4096

typedef __bf16 v8bf __attribute__((ext_vector_type(8)));
typedef float  v4f  __attribute__((ext_vector_type(4)));

__device__ __forceinline__ unsigned short f2bf(float f) {
  unsigned int u = __float_as_uint(f);
  u += 0x7fffu + ((u >> 16) & 1u);          // round-to-nearest-even
  return (unsigned short)(u >> 16);
}
__device__ __forceinline__ float bf2f(unsigned int h16) {
  return __uint_as_float(h16 << 16);
}

__device__ __forceinline__ void async_copy16(const void* g, void* l) {
  __builtin_amdgcn_global_load_lds(
      (__attribute__((address_space(1))) void*)g,
      (__attribute__((address_space(3))) void*)l, 16, 0, 0);
}

// --------------------------- x (fp32) -> bf16 ------------------------------
__global__ __launch_bounds__(256) void cvt_x_bf16(const float4* __restrict__ in,
                                                  uint4* __restrict__ out) {
  int i = blockIdx.x * 256 + threadIdx.x;   // one 8-float group per thread
  float4 a = in[2 * i], b = in[2 * i + 1];
  uint4 o;
  o.x = (unsigned)f2bf(a.x) | ((unsigned)f2bf(a.y) << 16);
  o.y = (unsigned)f2bf(a.z) | ((unsigned)f2bf(a.w) << 16);
  o.z = (unsigned)f2bf(b.x) | ((unsigned)f2bf(b.y) << 16);
  o.w = (unsigned)f2bf(b.z) | ((unsigned)f2bf(b.w) << 16);
  out[i] = o;
}

// ----------------- build M^T (bf16, [n][k]) with 64x64 tiles ---------------
// Tile (kt,nt) is entirely one case: diag (tw^2) / upper (bbw) / lower (0).
__global__ __launch_bounds__(256) void build_Mt(const float* __restrict__ tw,
                                                const float* __restrict__ bbw,
                                                unsigned short* __restrict__ Mt) {
  const int kt = blockIdx.x, nt = blockIdx.y;
  const int t = threadIdx.x;
  const int jj = t & 63, i0 = t >> 6;
  __shared__ float tile[64 * 65];
  if (kt <= nt) {
    const bool diag = (kt == nt);
    const float* S = diag ? tw : bbw;
    #pragma unroll
    for (int r = 0; r < 16; ++r) {
      int i = i0 + r * 4;                                   // k-local
      float v = S[(size_t)(kt * 64 + i) * DIM + nt * 64 + jj];
      tile[i * 65 + jj] = diag ? v * v : v;
    }
    __syncthreads();
    #pragma unroll
    for (int r = 0; r < 16; ++r) {
      int nl = i0 + r * 4;                                  // n-local
      Mt[(size_t)(nt * 64 + nl) * DIM + kt * 64 + jj] = f2bf(tile[jj * 65 + nl]);
    }
  } else {
    #pragma unroll
    for (int r = 0; r < 16; ++r) {
      int nl = i0 + r * 4;
      Mt[(size_t)(nt * 64 + nl) * DIM + kt * 64 + jj] = 0;
    }
  }
}

// --------------------------- main GEMM + epilogue --------------------------
// C[8192,4096] = Xb @ M  (M block-upper-tri => K loop only to (jc+1)*128)
// 128x128 tile, BK=64, 4 waves (2x2), each wave 64x64 via 4x4 mfma 16x16x32.
__global__ __launch_bounds__(256) void gemm_tree(
    const unsigned short* __restrict__ Xb,    // [8192][4096] bf16
    const unsigned short* __restrict__ Mt,    // [4096 n][4096 k] bf16 (M^T)
    const float* __restrict__ Xi,             // x_init fp32
    unsigned short* __restrict__ H,           // h out, bf16
    float* __restrict__ colsum,
    float* __restrict__ colsumsq) {
  __shared__ unsigned short As[128 * 64];     // [row][k]
  __shared__ unsigned short Bs[128 * 64];     // [n][k]

  const int jc = 31 - (int)blockIdx.x;        // heavy col-tiles dispatch first
  const int bm = (int)blockIdx.y;
  const int tid = threadIdx.x;
  const int wave = tid >> 6, lane = tid & 63;
  const int wm = (wave & 1) * 64, wn = (wave >> 1) * 64;
  const int lr = lane & 15, quad = lane >> 4;

  v4f acc[4][4];
  #pragma unroll
  for (int mi = 0; mi < 4; ++mi)
    #pragma unroll
    for (int ni = 0; ni < 4; ++ni) acc[mi][ni] = {0.f, 0.f, 0.f, 0.f};

  const int Kend = (jc + 1) * 128;
  const int srow = lane >> 3;                 // staging row-in-segment
  const int scol = (lane & 7) * 8;            // staging k offset

  for (int k0 = 0; k0 < Kend; k0 += 64) {
    #pragma unroll
    for (int r = 0; r < 4; ++r) {
      int seg = wave * 4 + r;                 // 16 segments x 1KB per tile
      int row = seg * 8 + srow;
      const unsigned short* ga = Xb + (size_t)(bm * 128 + row) * DIM + (k0 + scol);
      const unsigned short* gb = Mt + (size_t)(jc * 128 + row) * DIM + (k0 + scol);
      async_copy16(ga, &As[seg * 512]);       // lane scatter = lane*16B
      async_copy16(gb, &Bs[seg * 512]);
    }
    __syncthreads();
    #pragma unroll
    for (int kk = 0; kk < 2; ++kk) {
      v8bf a[4], b[4];
      #pragma unroll
      for (int mi = 0; mi < 4; ++mi)
        a[mi] = *(const v8bf*)&As[(wm + mi * 16 + lr) * 64 + kk * 32 + quad * 8];
      #pragma unroll
      for (int ni = 0; ni < 4; ++ni)
        b[ni] = *(const v8bf*)&Bs[(wn + ni * 16 + lr) * 64 + kk * 32 + quad * 8];
      #pragma unroll
      for (int mi = 0; mi < 4; ++mi)
        #pragma unroll
        for (int ni = 0; ni < 4; ++ni)
          acc[mi][ni] = __builtin_amdgcn_mfma_f32_16x16x32_bf16(
              a[mi], b[ni], acc[mi][ni], 0, 0, 0);
    }
    __syncthreads();
  }

  // Epilogue: h = acc + x_init; store bf16 h; per-column sum/sumsq atomics.
  // C/D layout: col = lane&15, row = quad*4 + reg  [m89/m91 verified]
  const int colT = jc * 128 + wn + lr;
  const int rowT = bm * 128 + wm + quad * 4;
  #pragma unroll
  for (int ni = 0; ni < 4; ++ni) {
    int col = colT + ni * 16;
    float s = 0.f, sq = 0.f;
    #pragma unroll
    for (int mi = 0; mi < 4; ++mi) {
      int row = rowT + mi * 16;
      #pragma unroll
      for (int r = 0; r < 4; ++r) {
        size_t idx = (size_t)(row + r) * DIM + col;
        float h = acc[mi][ni][r] + Xi[idx];
        H[idx] = f2bf(h);
        s += h;
        sq += h * h;
      }
    }
    // lanes l, l+16, l+32, l+48 hold the same column -> xor-reduce over quads
    s += __shfl_xor(s, 16);  s += __shfl_xor(s, 32);
    sq += __shfl_xor(sq, 16); sq += __shfl_xor(sq, 32);
    if (quad == 0) {
      atomicAdd(&colsum[col], s);
      atomicAdd(&colsumsq[col], sq);
    }
  }
}

// ------------------------- column stats -> mean/scale ----------------------
__global__ __launch_bounds__(256) void finalize_stats(
    const float* __restrict__ colsum, const float* __restrict__ colsumsq,
    float* __restrict__ mean, float* __restrict__ scale) {
  int i = blockIdx.x * 256 + threadIdx.x;
  float m = colsum[i] * (1.0f / BATCH);
  float var = fmaxf(colsumsq[i] * (1.0f / BATCH) - m * m, 0.0f);
  mean[i] = m;
  scale[i] = 1.0f / (sqrtf(var) + 1e-6f);     // (h-mean)*tree_scale^2 = (h-mean)/(std+eps)
}

// ------------------------- normalize + sigmoid -----------------------------
__global__ __launch_bounds__(256) void norm_sigmoid(
    const uint4* __restrict__ H, const float* __restrict__ mean,
    const float* __restrict__ scale, float4* __restrict__ out) {
  int i = blockIdx.x * 256 + threadIdx.x;     // 8-elem group, row-major
  int cg = (i & 511) << 3;                    // column of first element
  uint4 h = H[i];
  float hv[8];
  hv[0] = bf2f(h.x & 0xffffu); hv[1] = bf2f(h.x >> 16);
  hv[2] = bf2f(h.y & 0xffffu); hv[3] = bf2f(h.y >> 16);
  hv[4] = bf2f(h.z & 0xffffu); hv[5] = bf2f(h.z >> 16);
  hv[6] = bf2f(h.w & 0xffffu); hv[7] = bf2f(h.w >> 16);
  #pragma unroll
  for (int j = 0; j < 8; ++j) {
    float z = (hv[j] - mean[cg + j]) * scale[cg + j];
    hv[j] = 1.0f / (1.0f + __expf(-z));
  }
  out[2 * i]     = make_float4(hv[0], hv[1], hv[2], hv[3]);
  out[2 * i + 1] = make_float4(hv[4], hv[5], hv[6], hv[7]);
}

// ---------------------------------------------------------------------------
extern "C" void kernel_launch(void* const* d_in, const int* in_sizes, int n_in,
                              void* d_out, int out_size, void* d_ws, size_t ws_size,
                              hipStream_t stream) {
  const float* x      = (const float*)d_in[0];
  const float* x_init = (const float*)d_in[1];
  const float* tw     = (const float*)d_in[2];
  const float* bbw    = (const float*)d_in[3];
  float* out = (float*)d_out;

  char* ws = (char*)d_ws;
  // ws layout: Xb 64MB | Mt 32MB | H 64MB | colsum/colsumsq/mean/scale 4x16KB
  unsigned short* Xb = (unsigned short*)(ws);
  unsigned short* Mt = (unsigned short*)(ws + (size_t)67108864);
  unsigned short* H  = (unsigned short*)(ws + (size_t)100663296);
  float* colsum   = (float*)(ws + (size_t)167772160);
  float* colsumsq = (float*)(ws + (size_t)167772160 + 16384);
  float* mean     = (float*)(ws + (size_t)167772160 + 32768);
  float* scale    = (float*)(ws + (size_t)167772160 + 49152);

  // ws is re-poisoned to 0xAA before every timed launch -> zero accumulators.
  hipMemsetAsync(colsum, 0, 32768, stream);

  cvt_x_bf16<<<(BATCH * DIM / 8 + 255) / 256, 256, 0, stream>>>(
      (const float4*)x, (uint4*)Xb);
  build_Mt<<<dim3(64, 64), 256, 0, stream>>>(tw, bbw, Mt);
  gemm_tree<<<dim3(32, 64), 256, 0, stream>>>(Xb, Mt, x_init, H, colsum, colsumsq);
  finalize_stats<<<16, 256, 0, stream>>>(colsum, colsumsq, mean, scale);
  norm_sigmoid<<<(BATCH * DIM / 8 + 255) / 256, 256, 0, stream>>>(
      (const uint4*)H, mean, scale, (float4*)out);
}

// Round 2
// 599.675 us; speedup vs baseline: 1.2935x; 1.2935x over previous
//
#include <hip/hip_runtime.h>
#include <stdint.h>

// ---------------------------------------------------------------------------
// TreeLayer: h = x @ M + x_init, M = tw^2*blockdiag + bbw*strict_block_upper
// (block-upper-triangular incl. diagonal), then per-column ActNorm + sigmoid.
// bf16 MFMA GEMM. R1: XOR-swizzled LDS (kills 16-way bank conflicts),
// jc-major block ordering (load balance).
// ---------------------------------------------------------------------------

#define BATCH 8192
#define DIM   4096

typedef __bf16 v8bf __attribute__((ext_vector_type(8)));
typedef float  v4f  __attribute__((ext_vector_type(4)));

__device__ __forceinline__ unsigned short f2bf(float f) {
  unsigned int u = __float_as_uint(f);
  u += 0x7fffu + ((u >> 16) & 1u);          // round-to-nearest-even
  return (unsigned short)(u >> 16);
}
__device__ __forceinline__ float bf2f(unsigned int h16) {
  return __uint_as_float(h16 << 16);
}

__device__ __forceinline__ void async_copy16(const void* g, void* l) {
  __builtin_amdgcn_global_load_lds(
      (__attribute__((address_space(1))) void*)g,
      (__attribute__((address_space(3))) void*)l, 16, 0, 0);
}

// --------------------------- x (fp32) -> bf16 ------------------------------
__global__ __launch_bounds__(256) void cvt_x_bf16(const float4* __restrict__ in,
                                                  uint4* __restrict__ out) {
  int i = blockIdx.x * 256 + threadIdx.x;   // one 8-float group per thread
  float4 a = in[2 * i], b = in[2 * i + 1];
  uint4 o;
  o.x = (unsigned)f2bf(a.x) | ((unsigned)f2bf(a.y) << 16);
  o.y = (unsigned)f2bf(a.z) | ((unsigned)f2bf(a.w) << 16);
  o.z = (unsigned)f2bf(b.x) | ((unsigned)f2bf(b.y) << 16);
  o.w = (unsigned)f2bf(b.z) | ((unsigned)f2bf(b.w) << 16);
  out[i] = o;
}

// ----------------- build M^T (bf16, [n][k]) with 64x64 tiles ---------------
// Tile (kt,nt) is entirely one case: diag (tw^2) / upper (bbw) / lower (0).
__global__ __launch_bounds__(256) void build_Mt(const float* __restrict__ tw,
                                                const float* __restrict__ bbw,
                                                unsigned short* __restrict__ Mt) {
  const int kt = blockIdx.x, nt = blockIdx.y;
  const int t = threadIdx.x;
  const int jj = t & 63, i0 = t >> 6;
  __shared__ float tile[64 * 65];
  if (kt <= nt) {
    const bool diag = (kt == nt);
    const float* S = diag ? tw : bbw;
    #pragma unroll
    for (int r = 0; r < 16; ++r) {
      int i = i0 + r * 4;                                   // k-local
      float v = S[(size_t)(kt * 64 + i) * DIM + nt * 64 + jj];
      tile[i * 65 + jj] = diag ? v * v : v;
    }
    __syncthreads();
    #pragma unroll
    for (int r = 0; r < 16; ++r) {
      int nl = i0 + r * 4;                                  // n-local
      Mt[(size_t)(nt * 64 + nl) * DIM + kt * 64 + jj] = f2bf(tile[jj * 65 + nl]);
    }
  } else {
    #pragma unroll
    for (int r = 0; r < 16; ++r) {
      int nl = i0 + r * 4;
      Mt[(size_t)(nt * 64 + nl) * DIM + kt * 64 + jj] = 0;
    }
  }
}

// --------------------------- main GEMM + epilogue --------------------------
// C[8192,4096] = Xb @ M  (M block-upper-tri => K loop only to (jc+1)*128)
// 128x128 tile, BK=64, 4 waves (2x2), each wave 64x64 via 4x4 mfma 16x16x32.
// LDS layout XOR-swizzled: within each 128B row, 16B chunk c stored at
// position c ^ (row & 7). Staging fetches the swizzled source chunk (stays
// within the same 128B line -> coalescing preserved); fragment reads then
// hit 8 distinct 4-bank groups per quad (2-way aliasing only = free).
__global__ __launch_bounds__(256) void gemm_tree(
    const unsigned short* __restrict__ Xb,    // [8192][4096] bf16
    const unsigned short* __restrict__ Mt,    // [4096 n][4096 k] bf16 (M^T)
    const float* __restrict__ Xi,             // x_init fp32
    unsigned short* __restrict__ H,           // h out, bf16
    float* __restrict__ colsum,
    float* __restrict__ colsumsq) {
  __shared__ unsigned short As[128 * 64];     // [row][k] (swizzled)
  __shared__ unsigned short Bs[128 * 64];     // [n][k]   (swizzled)

  const int bid = (int)blockIdx.x;            // jc-major: heavy tiles first
  const int jc = 31 - (bid >> 6);
  const int bm = bid & 63;
  const int tid = threadIdx.x;
  const int wave = tid >> 6, lane = tid & 63;
  const int wm = (wave & 1) * 64, wn = (wave >> 1) * 64;
  const int lr = lane & 15, quad = lane >> 4;

  v4f acc[4][4];
  #pragma unroll
  for (int mi = 0; mi < 4; ++mi)
    #pragma unroll
    for (int ni = 0; ni < 4; ++ni) acc[mi][ni] = {0.f, 0.f, 0.f, 0.f};

  const int Kend = (jc + 1) * 128;
  const int srow = lane >> 3;                       // row within 8-row segment
  const int scol = ((lane & 7) ^ srow) * 8;         // swizzled source k-chunk

  for (int k0 = 0; k0 < Kend; k0 += 64) {
    #pragma unroll
    for (int r = 0; r < 4; ++r) {
      int seg = wave * 4 + r;                 // 16 segments x 1KB per tile
      int row = seg * 8 + srow;
      const unsigned short* ga = Xb + (size_t)(bm * 128 + row) * DIM + (k0 + scol);
      const unsigned short* gb = Mt + (size_t)(jc * 128 + row) * DIM + (k0 + scol);
      async_copy16(ga, &As[seg * 512]);       // HW lane scatter = lane*16B
      async_copy16(gb, &Bs[seg * 512]);
    }
    __syncthreads();
    #pragma unroll
    for (int kk = 0; kk < 2; ++kk) {
      const int sw = ((kk * 4 + quad) ^ (lr & 7)) * 8;   // swizzled chunk offset
      v8bf a[4], b[4];
      #pragma unroll
      for (int mi = 0; mi < 4; ++mi)
        a[mi] = *(const v8bf*)&As[(wm + mi * 16 + lr) * 64 + sw];
      #pragma unroll
      for (int ni = 0; ni < 4; ++ni)
        b[ni] = *(const v8bf*)&Bs[(wn + ni * 16 + lr) * 64 + sw];
      #pragma unroll
      for (int mi = 0; mi < 4; ++mi)
        #pragma unroll
        for (int ni = 0; ni < 4; ++ni)
          acc[mi][ni] = __builtin_amdgcn_mfma_f32_16x16x32_bf16(
              a[mi], b[ni], acc[mi][ni], 0, 0, 0);
    }
    __syncthreads();
  }

  // Epilogue: h = acc + x_init; store bf16 h; per-column sum/sumsq atomics.
  // C/D layout: col = lane&15, row = quad*4 + reg  [m89/m91 verified]
  const int colT = jc * 128 + wn + lr;
  const int rowT = bm * 128 + wm + quad * 4;
  #pragma unroll
  for (int ni = 0; ni < 4; ++ni) {
    int col = colT + ni * 16;
    float s = 0.f, sq = 0.f;
    #pragma unroll
    for (int mi = 0; mi < 4; ++mi) {
      int row = rowT + mi * 16;
      #pragma unroll
      for (int r = 0; r < 4; ++r) {
        size_t idx = (size_t)(row + r) * DIM + col;
        float h = acc[mi][ni][r] + Xi[idx];
        H[idx] = f2bf(h);
        s += h;
        sq += h * h;
      }
    }
    // lanes l, l+16, l+32, l+48 hold the same column -> xor-reduce over quads
    s += __shfl_xor(s, 16);  s += __shfl_xor(s, 32);
    sq += __shfl_xor(sq, 16); sq += __shfl_xor(sq, 32);
    if (quad == 0) {
      atomicAdd(&colsum[col], s);
      atomicAdd(&colsumsq[col], sq);
    }
  }
}

// ------------------------- column stats -> mean/scale ----------------------
__global__ __launch_bounds__(256) void finalize_stats(
    const float* __restrict__ colsum, const float* __restrict__ colsumsq,
    float* __restrict__ mean, float* __restrict__ scale) {
  int i = blockIdx.x * 256 + threadIdx.x;
  float m = colsum[i] * (1.0f / BATCH);
  float var = fmaxf(colsumsq[i] * (1.0f / BATCH) - m * m, 0.0f);
  mean[i] = m;
  scale[i] = 1.0f / (sqrtf(var) + 1e-6f);     // (h-mean)*tree_scale^2 = (h-mean)/(std+eps)
}

// ------------------------- normalize + sigmoid -----------------------------
__global__ __launch_bounds__(256) void norm_sigmoid(
    const uint4* __restrict__ H, const float* __restrict__ mean,
    const float* __restrict__ scale, float4* __restrict__ out) {
  int i = blockIdx.x * 256 + threadIdx.x;     // 8-elem group, row-major
  int cg = (i & 511) << 3;                    // column of first element
  uint4 h = H[i];
  float4 m0 = *(const float4*)&mean[cg],  m1 = *(const float4*)&mean[cg + 4];
  float4 s0 = *(const float4*)&scale[cg], s1 = *(const float4*)&scale[cg + 4];
  float hv[8];
  hv[0] = bf2f(h.x & 0xffffu); hv[1] = bf2f(h.x >> 16);
  hv[2] = bf2f(h.y & 0xffffu); hv[3] = bf2f(h.y >> 16);
  hv[4] = bf2f(h.z & 0xffffu); hv[5] = bf2f(h.z >> 16);
  hv[6] = bf2f(h.w & 0xffffu); hv[7] = bf2f(h.w >> 16);
  float mm[8] = {m0.x, m0.y, m0.z, m0.w, m1.x, m1.y, m1.z, m1.w};
  float ss[8] = {s0.x, s0.y, s0.z, s0.w, s1.x, s1.y, s1.z, s1.w};
  #pragma unroll
  for (int j = 0; j < 8; ++j) {
    float z = (hv[j] - mm[j]) * ss[j];
    hv[j] = 1.0f / (1.0f + __expf(-z));
  }
  out[2 * i]     = make_float4(hv[0], hv[1], hv[2], hv[3]);
  out[2 * i + 1] = make_float4(hv[4], hv[5], hv[6], hv[7]);
}

// ---------------------------------------------------------------------------
extern "C" void kernel_launch(void* const* d_in, const int* in_sizes, int n_in,
                              void* d_out, int out_size, void* d_ws, size_t ws_size,
                              hipStream_t stream) {
  const float* x      = (const float*)d_in[0];
  const float* x_init = (const float*)d_in[1];
  const float* tw     = (const float*)d_in[2];
  const float* bbw    = (const float*)d_in[3];
  float* out = (float*)d_out;

  char* ws = (char*)d_ws;
  // ws layout: Xb 64MB | Mt 32MB | H 64MB | colsum/colsumsq/mean/scale 4x16KB
  unsigned short* Xb = (unsigned short*)(ws);
  unsigned short* Mt = (unsigned short*)(ws + (size_t)67108864);
  unsigned short* H  = (unsigned short*)(ws + (size_t)100663296);
  float* colsum   = (float*)(ws + (size_t)167772160);
  float* colsumsq = (float*)(ws + (size_t)167772160 + 16384);
  float* mean     = (float*)(ws + (size_t)167772160 + 32768);
  float* scale    = (float*)(ws + (size_t)167772160 + 49152);

  // ws is re-poisoned to 0xAA before every timed launch -> zero accumulators.
  hipMemsetAsync(colsum, 0, 32768, stream);

  cvt_x_bf16<<<(BATCH * DIM / 8 + 255) / 256, 256, 0, stream>>>(
      (const float4*)x, (uint4*)Xb);
  build_Mt<<<dim3(64, 64), 256, 0, stream>>>(tw, bbw, Mt);
  gemm_tree<<<2048, 256, 0, stream>>>(Xb, Mt, x_init, H, colsum, colsumsq);
  finalize_stats<<<16, 256, 0, stream>>>(colsum, colsumsq, mean, scale);
  norm_sigmoid<<<(BATCH * DIM / 8 + 255) / 256, 256, 0, stream>>>(
      (const uint4*)H, mean, scale, (float4*)out);
}